// Round 1
// 825.559 us; speedup vs baseline: 1.1304x; 1.1304x over previous
//
#include <hip/hip_runtime.h>
#include <math.h>

// Problem constants (from setup_inputs): B=16, K=6, H=W=640
#define BB   16
#define KCH  6
#define CH   7          // K+1 channels in pred
#define NN   409600     // H*W
#define N4   102400     // NN/4 (float4 count)
#define EPSF 1e-6f

// Workspace layout in 32-bit words:
//   hist[BB][65536]        : 1048576 words (reused: pass-A top16 hist, then refine low16 hist)
//   pos/negtot/prefix/rank/thr/useohem [BB] each
//   textsums[BB][3], kernsums[BB*KCH][3]
//   kmask bytes [BB][N4] (uchar4 per float4) -- NOT zeroed
#define HIST_OFF 0u
#define POS_OFF  1048576u
#define NEGT_OFF 1048592u
#define PRE_OFF  1048608u
#define RANK_OFF 1048624u
#define THR_OFF  1048640u
#define UOH_OFF  1048656u
#define TEXT_OFF 1048672u   // 48 floats
#define KERN_OFF 1048720u   // 96*3 = 288 floats
#define ZERO_END 1049008u   // words to memset
#define KM_OFF   1049008u   // kmask: BB*N4 words
#define WS_WORDS (KM_OFF + BB * N4)   // ~10.75 MB

__device__ __forceinline__ unsigned sortkey(float f) {
    // monotone float->uint map (ascending float == ascending uint)
    unsigned u = __float_as_uint(f);
    return (u & 0x80000000u) ? ~u : (u | 0x80000000u);
}
__device__ __forceinline__ float sigmoidf_(float x) { return 1.0f / (1.0f + expf(-x)); }

__device__ __forceinline__ float wred(float v) {
#pragma unroll
    for (int o = 32; o > 0; o >>= 1) v += __shfl_down(v, o, 64);
    return v;
}
__device__ __forceinline__ unsigned wredu(unsigned v) {
#pragma unroll
    for (int o = 32; o > 0; o >>= 1) v += __shfl_down(v, o, 64);
    return v;
}

// Pass A: per-batch pos/neg counts + 16-bit (top) histogram of neg sort keys
// (global atomics) + kmask bytes for the kernel-dice pass.
__global__ __launch_bounds__(256) void k_passA(const float* __restrict__ pred,
                                               const float* __restrict__ gt,
                                               const float* __restrict__ tm,
                                               unsigned* __restrict__ ws) {
    const int b = blockIdx.y;
    const int t = threadIdx.x;
    const float4* p4 = (const float4*)(pred + (size_t)b * CH * NN + (size_t)KCH * NN);
    const float4* g4 = (const float4*)(gt + (size_t)b * NN);
    const float4* m4 = (const float4*)(tm + (size_t)b * NN);
    unsigned* hist = ws + HIST_OFF + (size_t)b * 65536u;
    unsigned* km   = ws + KM_OFF + (size_t)b * N4;

    unsigned lpos = 0, lneg = 0;
    for (int i = blockIdx.x * 256 + t; i < N4; i += gridDim.x * 256) {
        float4 p = p4[i], g = g4[i], m = m4[i];
        unsigned kb = 0u;
#pragma unroll
        for (int j = 0; j < 4; j++) {
            float pf = (&p.x)[j], gf = (&g.x)[j], mf = (&m.x)[j];
            bool neg = (gf <= 0.5f);
            lneg += neg ? 1u : 0u;
            lpos += (gf > 0.5f && mf > 0.5f) ? 1u : 0u;
            kb |= ((pf > 0.f && mf > 0.5f) ? 1u : 0u) << (8 * j);
            if (neg) atomicAdd(&hist[sortkey(pf) >> 16], 1u);
        }
        km[i] = kb;
    }
    lpos = wredu(lpos); lneg = wredu(lneg);
    if ((t & 63) == 0) {
        atomicAdd(&ws[POS_OFF + b], lpos);
        atomicAdd(&ws[NEGT_OFF + b], lneg);
    }
}

// Refine: histogram low 16 bits of keys whose top 16 bits match the prefix.
__global__ __launch_bounds__(256) void k_refine(const float* __restrict__ pred,
                                                const float* __restrict__ gt,
                                                unsigned* __restrict__ ws) {
    const int b = blockIdx.y;
    const unsigned pre = ws[PRE_OFF + b];
    const float4* p4 = (const float4*)(pred + (size_t)b * CH * NN + (size_t)KCH * NN);
    const float4* g4 = (const float4*)(gt + (size_t)b * NN);
    unsigned* hist = ws + HIST_OFF + (size_t)b * 65536u;

    for (int i = blockIdx.x * 256 + threadIdx.x; i < N4; i += gridDim.x * 256) {
        float4 p = p4[i], g = g4[i];
#pragma unroll
        for (int j = 0; j < 4; j++) {
            float pf = (&p.x)[j], gf = (&g.x)[j];
            if (gf <= 0.5f) {
                unsigned key = sortkey(pf);
                if ((key >> 16) == pre) atomicAdd(&hist[key & 0xFFFFu], 1u);
            }
        }
    }
}

// Parallel select over 65536 bins: one block per batch.
// pass 0: find top-16 prefix + remaining rank, then zero hist for reuse.
// pass 1: find low-16 bits -> exact threshold float bits.
__global__ __launch_bounds__(256) void k_select(unsigned* __restrict__ ws, int pass) {
    const int b = blockIdx.x;
    const int t = threadIdx.x;
    unsigned* hist = ws + HIST_OFF + (size_t)b * 65536u;
    __shared__ unsigned S[256];
    __shared__ unsigned s_r, s_csel, s_above, s_found;

    if (t == 0) {
        unsigned r;
        if (pass == 0) {
            unsigned pos = ws[POS_OFF + b];
            unsigned ntot = ws[NEGT_OFF + b];
            unsigned negnum = min(3u * pos, ntot);
            ws[UOH_OFF + b] = (pos > 0u && negnum > 0u) ? 1u : 0u;
            r = (negnum > 0u) ? negnum : 1u;   // rank from top (1-indexed)
        } else {
            r = ws[RANK_OFF + b];
        }
        s_r = r;
        s_found = 0u;
    }
    __syncthreads();
    const unsigned r = s_r;

    // chunk sums: thread t sums bins [t*256, t*256+256) via uint4 loads
    {
        const uint4* hp = (const uint4*)(hist + (size_t)t * 256u);
        unsigned ms = 0;
#pragma unroll 8
        for (int i = 0; i < 64; i++) {
            uint4 h = hp[i];
            ms += h.x + h.y + h.z + h.w;
        }
        S[t] = ms;
    }
    __syncthreads();
    // suffix inclusive scan: S[t] = sum over chunks >= t
#pragma unroll
    for (int off = 1; off < 256; off <<= 1) {
        unsigned v = (t + off < 256) ? S[t + off] : 0u;
        __syncthreads();
        S[t] += v;
        __syncthreads();
    }
    {
        unsigned Sc = S[t];
        unsigned Sc1 = (t == 255) ? 0u : S[t + 1];
        if (Sc >= r && Sc1 < r) { s_csel = (unsigned)t; s_above = Sc1; s_found = 1u; }
    }
    __syncthreads();

    if (s_found) {
        const unsigned csel = s_csel;
        const unsigned rr = r - s_above;   // rank within selected chunk
        S[t] = hist[csel * 256u + t];
        __syncthreads();
#pragma unroll
        for (int off = 1; off < 256; off <<= 1) {
            unsigned v = (t + off < 256) ? S[t + off] : 0u;
            __syncthreads();
            S[t] += v;
            __syncthreads();
        }
        unsigned Ti = S[t];
        unsigned Ti1 = (t == 255) ? 0u : S[t + 1];
        if (Ti >= rr && Ti1 < rr) {
            unsigned bin = csel * 256u + (unsigned)t;
            if (pass == 0) {
                ws[PRE_OFF + b] = bin;            // 16-bit prefix
                ws[RANK_OFF + b] = rr - Ti1;      // remaining rank within prefix group
            } else {
                unsigned key = (ws[PRE_OFF + b] << 16) | bin;
                unsigned orig = (key & 0x80000000u) ? (key & 0x7FFFFFFFu) : ~key;
                ws[THR_OFF + b] = orig;
            }
        }
    } else if (t == 0) {
        // negtot == 0 (or empty refine) -> threshold unused (use_ohem = 0)
        ws[PRE_OFF + b] = 0u;
        ws[RANK_OFF + b] = 1u;
        if (pass == 1) ws[THR_OFF + b] = 0x7F800000u;  // +inf
    }
    __syncthreads();
    if (pass == 0) {
        // zero hist for the refine pass
        for (unsigned i = t; i < 65536u; i += 256u) hist[i] = 0u;
    }
}

// Text dice partial sums with OHEM-selected mask.
__global__ __launch_bounds__(256) void k_textdice(const float* __restrict__ pred,
                                                  const float* __restrict__ gt,
                                                  const float* __restrict__ tm,
                                                  unsigned* __restrict__ ws) {
    const int b = blockIdx.y;
    const float thr = __uint_as_float(ws[THR_OFF + b]);
    const bool useoh = (ws[UOH_OFF + b] != 0u);
    const float4* p4 = (const float4*)(pred + (size_t)b * CH * NN + (size_t)KCH * NN);
    const float4* g4 = (const float4*)(gt + (size_t)b * NN);
    const float4* m4 = (const float4*)(tm + (size_t)b * NN);

    float la = 0.f, lb = 0.f, lc = 0.f;
    for (int i = blockIdx.x * 256 + threadIdx.x; i < N4; i += gridDim.x * 256) {
        float4 p = p4[i], g = g4[i], m = m4[i];
#pragma unroll
        for (int j = 0; j < 4; j++) {
            float pf = (&p.x)[j], gf = (&g.x)[j], mf = (&m.x)[j];
            float sel;
            if (useoh)
                sel = (((pf >= thr) || (gf > 0.5f)) && (mf > 0.5f)) ? 1.f : 0.f;
            else
                sel = mf;
            float pp = sigmoidf_(pf) * sel;
            float gg = gf * sel;
            la += pp * gg; lb += pp * pp; lc += gg * gg;
        }
    }
    la = wred(la); lb = wred(lb); lc = wred(lc);
    float* ts = (float*)(ws + TEXT_OFF);
    if ((threadIdx.x & 63) == 0) {
        atomicAdd(&ts[b * 3 + 0], la);
        atomicAdd(&ts[b * 3 + 1], lb);
        atomicAdd(&ts[b * 3 + 2], lc);
    }
}

// Kernel-branch dice sums: one (b,k) slice per grid.y. Uses precomputed kmask
// bytes (L2-hot) instead of re-reading pred_texts/tm.
__global__ __launch_bounds__(256) void k_kern2(const float* __restrict__ pred,
                                               const float* __restrict__ gtk,
                                               unsigned* __restrict__ ws) {
    const int bk = blockIdx.y;
    const int b = bk / KCH;
    const int k = bk % KCH;
    const float4* pk4 = (const float4*)(pred + ((size_t)b * CH + k) * NN);
    const float4* gk4 = (const float4*)(gtk + ((size_t)b * KCH + k) * NN);
    const unsigned* km = ws + KM_OFF + (size_t)b * N4;

    float a0 = 0.f, a1 = 0.f, a2 = 0.f;
#pragma unroll 2
    for (int i = blockIdx.x * 256 + threadIdx.x; i < N4; i += gridDim.x * 256) {
        float4 p = pk4[i], g = gk4[i];
        unsigned kb = km[i];
#pragma unroll
        for (int j = 0; j < 4; j++) {
            float mm = (float)((kb >> (8 * j)) & 0xFFu);
            float pp = sigmoidf_((&p.x)[j]) * mm;
            float gg = (&g.x)[j] * mm;
            a0 += pp * gg; a1 += pp * pp; a2 += gg * gg;
        }
    }
    a0 = wred(a0); a1 = wred(a1); a2 = wred(a2);
    float* kf = (float*)(ws + KERN_OFF);
    if ((threadIdx.x & 63) == 0) {
        atomicAdd(&kf[bk * 3 + 0], a0);
        atomicAdd(&kf[bk * 3 + 1], a1);
        atomicAdd(&kf[bk * 3 + 2], a2);
    }
}

__global__ void k_final(const unsigned* __restrict__ ws, float* __restrict__ out) {
    if (threadIdx.x != 0 || blockIdx.x != 0) return;
    const float* ts = (const float*)(ws + TEXT_OFF);
    const float* ks = (const float*)(ws + KERN_OFF);
    float lt = 0.f;
    for (int b = 0; b < BB; b++) {
        float a = ts[b * 3 + 0], p2 = ts[b * 3 + 1], g2 = ts[b * 3 + 2];
        lt += 1.0f - 2.0f * a / (p2 + g2 + 2.0f * EPSF);
    }
    lt *= (1.0f / BB);
    float lk = 0.f;
    for (int i = 0; i < KCH * BB; i++) {
        float a = ks[i * 3 + 0], p2 = ks[i * 3 + 1], g2 = ks[i * 3 + 2];
        lk += 1.0f - 2.0f * a / (p2 + g2 + 2.0f * EPSF);
    }
    lk *= (1.0f / (KCH * BB));
    out[0] = 0.7f * lt + 0.3f * lk;
}

extern "C" void kernel_launch(void* const* d_in, const int* in_sizes, int n_in,
                              void* d_out, int out_size, void* d_ws, size_t ws_size,
                              hipStream_t stream) {
    const float* pred = (const float*)d_in[0];   // (16,7,640,640)
    const float* gt   = (const float*)d_in[1];   // (16,640,640)
    const float* gtk  = (const float*)d_in[2];   // (16,6,640,640)
    const float* tm   = (const float*)d_in[3];   // (16,640,640)
    float* out = (float*)d_out;
    unsigned* ws = (unsigned*)d_ws;

    hipMemsetAsync(ws, 0, (size_t)ZERO_END * 4, stream);

    dim3 blk(256);

    // counts + top-16 hist + kmask
    k_passA<<<dim3(100, BB), blk, 0, stream>>>(pred, gt, tm, ws);
    k_select<<<BB, blk, 0, stream>>>(ws, 0);
    k_refine<<<dim3(100, BB), blk, 0, stream>>>(pred, gt, ws);
    k_select<<<BB, blk, 0, stream>>>(ws, 1);
    k_textdice<<<dim3(100, BB), blk, 0, stream>>>(pred, gt, tm, ws);
    k_kern2<<<dim3(50, 96), blk, 0, stream>>>(pred, gtk, ws);
    k_final<<<1, 64, 0, stream>>>(ws, out);
}

// Round 2
// 652.242 us; speedup vs baseline: 1.4308x; 1.2657x over previous
//
#include <hip/hip_runtime.h>
#include <math.h>

// Problem constants (from setup_inputs): B=16, K=6, H=W=640
#define BB   16
#define KCH  6
#define CH   7          // K+1 channels in pred
#define NN   409600     // H*W
#define N4   102400     // NN/4 (float4 count)
#define EPSF 1e-6f

// Workspace layout in 32-bit words:
//   hist[BB][4096]  (reused across the three radix passes)
//   pos/negtot/prefix/rank/thr/useohem [BB] each
//   textsums[BB][3], kernsums[BB*KCH][3]
//   kmask bytes [BB][N4] (uchar4 per float4) -- NOT zeroed
#define HIST_OFF 0u
#define POS_OFF  65536u
#define NEGT_OFF 65552u
#define PRE_OFF  65568u
#define RANK_OFF 65584u
#define THR_OFF  65600u
#define UOH_OFF  65616u
#define TEXT_OFF 65632u    // 48 floats
#define KERN_OFF 65680u    // 96*3 = 288 floats
#define ZERO_END 65968u    // words to memset
#define KM_OFF   65968u    // kmask: BB*N4 words
#define WS_WORDS (KM_OFF + BB * N4)   // ~6.8 MB

__device__ __forceinline__ unsigned sortkey(float f) {
    // monotone float->uint map (ascending float == ascending uint)
    unsigned u = __float_as_uint(f);
    return (u & 0x80000000u) ? ~u : (u | 0x80000000u);
}
// fast sigmoid: v_exp + v_rcp (~3 ops vs ~30 for libm expf + exact div)
__device__ __forceinline__ float fsig(float x) {
    return __builtin_amdgcn_rcpf(1.0f + __expf(-x));
}

__device__ __forceinline__ float wred(float v) {
#pragma unroll
    for (int o = 32; o > 0; o >>= 1) v += __shfl_down(v, o, 64);
    return v;
}
__device__ __forceinline__ unsigned wredu(unsigned v) {
#pragma unroll
    for (int o = 32; o > 0; o >>= 1) v += __shfl_down(v, o, 64);
    return v;
}

// Pass A: per-batch pos/neg counts + top-12-bit LDS histogram of neg sort keys
// + kmask bytes for the kernel-dice pass. Grid (100, BB): stride 25600, 4
// iters/thread, unrolled x2 (exact).
__global__ __launch_bounds__(256) void k_passA(const float* __restrict__ pred,
                                               const float* __restrict__ gt,
                                               const float* __restrict__ tm,
                                               unsigned* __restrict__ ws) {
    const int b = blockIdx.y;
    const int t = threadIdx.x;
    const float4* p4 = (const float4*)(pred + (size_t)b * CH * NN + (size_t)KCH * NN);
    const float4* g4 = (const float4*)(gt + (size_t)b * NN);
    const float4* m4 = (const float4*)(tm + (size_t)b * NN);
    unsigned* km = ws + KM_OFF + (size_t)b * N4;
    unsigned* ghist = ws + HIST_OFF + (size_t)b * 4096u;

    __shared__ unsigned h[4096];
    for (int i = t; i < 4096; i += 256) h[i] = 0u;
    __syncthreads();

    unsigned lpos = 0, lneg = 0;
    const int i0 = blockIdx.x * 256 + t;
    for (int i = i0; i < N4; i += 51200) {
        const int i1 = i + 25600;
        float4 p0 = p4[i],  g0 = g4[i],  m0 = m4[i];
        float4 p1 = p4[i1], g1 = g4[i1], m1 = m4[i1];
        unsigned kb0 = 0u, kb1 = 0u;
#pragma unroll
        for (int j = 0; j < 4; j++) {
            float pf = (&p0.x)[j], gf = (&g0.x)[j], mf = (&m0.x)[j];
            bool neg = (gf <= 0.5f);
            lneg += neg ? 1u : 0u;
            lpos += (gf > 0.5f && mf > 0.5f) ? 1u : 0u;
            kb0 |= ((pf > 0.f && mf > 0.5f) ? 1u : 0u) << (8 * j);
            if (neg) atomicAdd(&h[sortkey(pf) >> 20], 1u);
        }
#pragma unroll
        for (int j = 0; j < 4; j++) {
            float pf = (&p1.x)[j], gf = (&g1.x)[j], mf = (&m1.x)[j];
            bool neg = (gf <= 0.5f);
            lneg += neg ? 1u : 0u;
            lpos += (gf > 0.5f && mf > 0.5f) ? 1u : 0u;
            kb1 |= ((pf > 0.f && mf > 0.5f) ? 1u : 0u) << (8 * j);
            if (neg) atomicAdd(&h[sortkey(pf) >> 20], 1u);
        }
        km[i] = kb0;
        km[i1] = kb1;
    }
    lpos = wredu(lpos); lneg = wredu(lneg);
    if ((t & 63) == 0) {
        atomicAdd(&ws[POS_OFF + b], lpos);
        atomicAdd(&ws[NEGT_OFF + b], lneg);
    }
    __syncthreads();
    // merge non-zero bins to the per-batch global histogram
    for (int i = t; i < 4096; i += 256) {
        unsigned c = h[i];
        if (c) atomicAdd(&ghist[i], c);
    }
}

// Refine: pass 1 = histogram bits 19..8 of keys matching 12-bit prefix;
// pass 2 = histogram bits 7..0 of keys matching 24-bit prefix.
__global__ __launch_bounds__(256) void k_refine(const float* __restrict__ pred,
                                                const float* __restrict__ gt,
                                                unsigned* __restrict__ ws, int pass) {
    const int b = blockIdx.y;
    const int t = threadIdx.x;
    const unsigned pre = ws[PRE_OFF + b];
    const float4* p4 = (const float4*)(pred + (size_t)b * CH * NN + (size_t)KCH * NN);
    const float4* g4 = (const float4*)(gt + (size_t)b * NN);
    unsigned* ghist = ws + HIST_OFF + (size_t)b * 4096u;
    const int nb = (pass == 1) ? 4096 : 256;

    __shared__ unsigned h[4096];
    for (int i = t; i < 4096; i += 256) h[i] = 0u;
    __syncthreads();

    const int i0 = blockIdx.x * 256 + t;
    for (int i = i0; i < N4; i += 51200) {
        const int i1 = i + 25600;
        float4 p0 = p4[i],  g0 = g4[i];
        float4 p1 = p4[i1], g1 = g4[i1];
#pragma unroll
        for (int j = 0; j < 4; j++) {
            float pf = (&p0.x)[j], gf = (&g0.x)[j];
            if (gf <= 0.5f) {
                unsigned key = sortkey(pf);
                if (pass == 1) { if ((key >> 20) == pre) atomicAdd(&h[(key >> 8) & 0xFFFu], 1u); }
                else           { if ((key >> 8)  == pre) atomicAdd(&h[key & 0xFFu], 1u); }
            }
        }
#pragma unroll
        for (int j = 0; j < 4; j++) {
            float pf = (&p1.x)[j], gf = (&g1.x)[j];
            if (gf <= 0.5f) {
                unsigned key = sortkey(pf);
                if (pass == 1) { if ((key >> 20) == pre) atomicAdd(&h[(key >> 8) & 0xFFFu], 1u); }
                else           { if ((key >> 8)  == pre) atomicAdd(&h[key & 0xFFu], 1u); }
            }
        }
    }
    __syncthreads();
    for (int i = t; i < nb; i += 256) {
        unsigned c = h[i];
        if (c) atomicAdd(&ghist[i], c);
    }
}

// Parallel select, one block per batch.
// pass 0: 4096 bins -> 12-bit prefix + rank; zero hist.
// pass 1: 4096 bins -> 24-bit prefix + rank; zero hist.
// pass 2: 256 bins  -> exact threshold float bits.
__global__ __launch_bounds__(256) void k_select(unsigned* __restrict__ ws, int pass) {
    const int b = blockIdx.x;
    const int t = threadIdx.x;
    unsigned* hist = ws + HIST_OFF + (size_t)b * 4096u;
    const int nb = (pass == 2) ? 256 : 4096;
    const int chk = nb / 256;
    __shared__ unsigned S[256];
    __shared__ unsigned s_r, s_csel, s_above, s_found;

    if (t == 0) {
        unsigned r;
        if (pass == 0) {
            unsigned pos = ws[POS_OFF + b];
            unsigned ntot = ws[NEGT_OFF + b];
            unsigned negnum = min(3u * pos, ntot);
            ws[UOH_OFF + b] = (pos > 0u && negnum > 0u) ? 1u : 0u;
            r = (negnum > 0u) ? negnum : 1u;   // rank from top (1-indexed)
        } else {
            r = ws[RANK_OFF + b];
        }
        s_r = r;
        s_found = 0u;
    }
    __syncthreads();
    const unsigned r = s_r;

    // chunk sums
    {
        unsigned ms = 0;
#pragma unroll 4
        for (int i = 0; i < chk; i++) ms += hist[t * chk + i];
        S[t] = ms;
    }
    __syncthreads();
    // suffix inclusive scan: S[t] = sum over chunks >= t
#pragma unroll
    for (int off = 1; off < 256; off <<= 1) {
        unsigned v = (t + off < 256) ? S[t + off] : 0u;
        __syncthreads();
        S[t] += v;
        __syncthreads();
    }
    {
        unsigned Sc = S[t];
        unsigned Sc1 = (t == 255) ? 0u : S[t + 1];
        if (Sc >= r && Sc1 < r) { s_csel = (unsigned)t; s_above = Sc1; s_found = 1u; }
    }
    __syncthreads();

    if (t == 0) {
        if (s_found) {
            const unsigned base = s_csel * (unsigned)chk;
            const unsigned rr = r - s_above;   // rank within selected chunk
            unsigned cum = 0, selbin = 0, rem = 1;
            for (int bin = chk - 1; bin >= 0; bin--) {
                unsigned c = hist[base + bin];
                if (cum + c >= rr) { selbin = base + (unsigned)bin; rem = rr - cum; break; }
                cum += c;
            }
            if (pass == 0) {
                ws[PRE_OFF + b] = selbin;
                ws[RANK_OFF + b] = rem;
            } else if (pass == 1) {
                ws[PRE_OFF + b] = (ws[PRE_OFF + b] << 12) | selbin;
                ws[RANK_OFF + b] = rem;
            } else {
                unsigned key = (ws[PRE_OFF + b] << 8) | selbin;
                unsigned orig = (key & 0x80000000u) ? (key & 0x7FFFFFFFu) : ~key;
                ws[THR_OFF + b] = orig;
            }
        } else {
            // no negatives at all -> threshold unused (use_ohem == 0)
            ws[PRE_OFF + b] = 0u;
            ws[RANK_OFF + b] = 1u;
            if (pass == 2) ws[THR_OFF + b] = 0x7F800000u;  // +inf
        }
    }
    __syncthreads();
    if (pass < 2) {
        for (int i = t; i < 4096; i += 256) hist[i] = 0u;
    }
}

// Text dice partial sums with OHEM-selected mask. Grid (100, BB), unrolled x2.
__global__ __launch_bounds__(256) void k_textdice(const float* __restrict__ pred,
                                                  const float* __restrict__ gt,
                                                  const float* __restrict__ tm,
                                                  unsigned* __restrict__ ws) {
    const int b = blockIdx.y;
    const float thr = __uint_as_float(ws[THR_OFF + b]);
    const bool useoh = (ws[UOH_OFF + b] != 0u);
    const float4* p4 = (const float4*)(pred + (size_t)b * CH * NN + (size_t)KCH * NN);
    const float4* g4 = (const float4*)(gt + (size_t)b * NN);
    const float4* m4 = (const float4*)(tm + (size_t)b * NN);

    float la = 0.f, lb = 0.f, lc = 0.f;
    const int i0 = blockIdx.x * 256 + threadIdx.x;
    for (int i = i0; i < N4; i += 51200) {
        const int i1 = i + 25600;
        float4 p0 = p4[i],  g0 = g4[i],  m0 = m4[i];
        float4 p1 = p4[i1], g1 = g4[i1], m1 = m4[i1];
#pragma unroll
        for (int j = 0; j < 4; j++) {
            float pf = (&p0.x)[j], gf = (&g0.x)[j], mf = (&m0.x)[j];
            float sel = useoh ? ((((pf >= thr) || (gf > 0.5f)) && (mf > 0.5f)) ? 1.f : 0.f)
                              : mf;
            float pp = fsig(pf) * sel;
            float gg = gf * sel;
            la += pp * gg; lb += pp * pp; lc += gg * gg;
        }
#pragma unroll
        for (int j = 0; j < 4; j++) {
            float pf = (&p1.x)[j], gf = (&g1.x)[j], mf = (&m1.x)[j];
            float sel = useoh ? ((((pf >= thr) || (gf > 0.5f)) && (mf > 0.5f)) ? 1.f : 0.f)
                              : mf;
            float pp = fsig(pf) * sel;
            float gg = gf * sel;
            la += pp * gg; lb += pp * pp; lc += gg * gg;
        }
    }
    la = wred(la); lb = wred(lb); lc = wred(lc);
    float* ts = (float*)(ws + TEXT_OFF);
    if ((threadIdx.x & 63) == 0) {
        atomicAdd(&ts[b * 3 + 0], la);
        atomicAdd(&ts[b * 3 + 1], lb);
        atomicAdd(&ts[b * 3 + 2], lc);
    }
}

// Kernel-branch dice sums: one (b,k) slice per grid.y. Grid (20, 96):
// stride 5120, 20 iters/thread, unrolled x2 (exact). 1920 blocks = one
// residency round (7.5 blocks/CU), no tail.
__global__ __launch_bounds__(256) void k_kern2(const float* __restrict__ pred,
                                               const float* __restrict__ gtk,
                                               unsigned* __restrict__ ws) {
    const int bk = blockIdx.y;
    const int b = bk / KCH;
    const int k = bk % KCH;
    const float4* pk4 = (const float4*)(pred + ((size_t)b * CH + k) * NN);
    const float4* gk4 = (const float4*)(gtk + ((size_t)b * KCH + k) * NN);
    const unsigned* km = ws + KM_OFF + (size_t)b * N4;

    float a0 = 0.f, a1 = 0.f, a2 = 0.f;
    const int i0 = blockIdx.x * 256 + threadIdx.x;
    for (int i = i0; i < N4; i += 10240) {
        const int i1 = i + 5120;
        float4 p0 = pk4[i],  g0 = gk4[i];
        float4 p1 = pk4[i1], g1 = gk4[i1];
        unsigned kb0 = km[i], kb1 = km[i1];
#pragma unroll
        for (int j = 0; j < 4; j++) {
            float mm = ((kb0 >> (8 * j)) & 1u) ? 1.f : 0.f;
            float pp = fsig((&p0.x)[j]) * mm;
            float gg = (&g0.x)[j] * mm;
            a0 += pp * gg; a1 += pp * pp; a2 += gg * gg;
        }
#pragma unroll
        for (int j = 0; j < 4; j++) {
            float mm = ((kb1 >> (8 * j)) & 1u) ? 1.f : 0.f;
            float pp = fsig((&p1.x)[j]) * mm;
            float gg = (&g1.x)[j] * mm;
            a0 += pp * gg; a1 += pp * pp; a2 += gg * gg;
        }
    }
    a0 = wred(a0); a1 = wred(a1); a2 = wred(a2);
    float* kf = (float*)(ws + KERN_OFF);
    if ((threadIdx.x & 63) == 0) {
        atomicAdd(&kf[bk * 3 + 0], a0);
        atomicAdd(&kf[bk * 3 + 1], a1);
        atomicAdd(&kf[bk * 3 + 2], a2);
    }
}

__global__ void k_final(const unsigned* __restrict__ ws, float* __restrict__ out) {
    if (threadIdx.x != 0 || blockIdx.x != 0) return;
    const float* ts = (const float*)(ws + TEXT_OFF);
    const float* ks = (const float*)(ws + KERN_OFF);
    float lt = 0.f;
    for (int b = 0; b < BB; b++) {
        float a = ts[b * 3 + 0], p2 = ts[b * 3 + 1], g2 = ts[b * 3 + 2];
        lt += 1.0f - 2.0f * a / (p2 + g2 + 2.0f * EPSF);
    }
    lt *= (1.0f / BB);
    float lk = 0.f;
    for (int i = 0; i < KCH * BB; i++) {
        float a = ks[i * 3 + 0], p2 = ks[i * 3 + 1], g2 = ks[i * 3 + 2];
        lk += 1.0f - 2.0f * a / (p2 + g2 + 2.0f * EPSF);
    }
    lk *= (1.0f / (KCH * BB));
    out[0] = 0.7f * lt + 0.3f * lk;
}

extern "C" void kernel_launch(void* const* d_in, const int* in_sizes, int n_in,
                              void* d_out, int out_size, void* d_ws, size_t ws_size,
                              hipStream_t stream) {
    const float* pred = (const float*)d_in[0];   // (16,7,640,640)
    const float* gt   = (const float*)d_in[1];   // (16,640,640)
    const float* gtk  = (const float*)d_in[2];   // (16,6,640,640)
    const float* tm   = (const float*)d_in[3];   // (16,640,640)
    float* out = (float*)d_out;
    unsigned* ws = (unsigned*)d_ws;

    hipMemsetAsync(ws, 0, (size_t)ZERO_END * 4, stream);

    dim3 blk(256);

    k_passA<<<dim3(100, BB), blk, 0, stream>>>(pred, gt, tm, ws);
    k_select<<<BB, blk, 0, stream>>>(ws, 0);
    k_refine<<<dim3(100, BB), blk, 0, stream>>>(pred, gt, ws, 1);
    k_select<<<BB, blk, 0, stream>>>(ws, 1);
    k_refine<<<dim3(100, BB), blk, 0, stream>>>(pred, gt, ws, 2);
    k_select<<<BB, blk, 0, stream>>>(ws, 2);
    k_textdice<<<dim3(100, BB), blk, 0, stream>>>(pred, gt, tm, ws);
    k_kern2<<<dim3(20, 96), blk, 0, stream>>>(pred, gtk, ws);
    k_final<<<1, 64, 0, stream>>>(ws, out);
}